// Round 1
// baseline (125.626 us; speedup 1.0000x reference)
//
#include <hip/hip_runtime.h>

// AtomEncoderLayer fused single-kernel: B=4, N=32, D=128, H=8, NC=27, DK=16,
// DFF=512, L=864. One block per (b,i), 512 threads, NO pre-kernel:
// all former k_pre quantities are contracted away block-locally:
//   u_h[e]   = Wk[e, h-slice] · q[h-slice]          (8 x 128)
//   qAxk[h][n] = sum_e xh_n[e] g1[e] u_h[e]
//   qGk[h][j]  = sum_e w_j[e] g1[e] u_h[e]
//   S3[h]      = q·bk|_h + sum_e b1[e] u_h[e]
//   att_d      = sum_e ZZ_h[e] Wv[e][d] + bv[d],
//   ZZ_h[e]    = (sum_n Tn[h][n] xh_n[e] + sum_j RD[h][j] w_j[e]) g1[e]/S_h + b1[e]
// so no Axk/Axv/qbuf globals, no second launch, no inter-kernel drain.

#define B_ 4
#define N_ 32
#define D_ 128
#define H_ 8
#define NC_ 27
#define DFF_ 512
#define L_ (NC_*N_)        // 864

__device__ __forceinline__ float wave_red_sum(float v){
  #pragma unroll
  for (int off = 32; off; off >>= 1) v += __shfl_xor(v, off);
  return v;
}

// dual block-wide sum, blockDim = 512 (8 waves), double-buffered by phase
__device__ __forceinline__ void bred2(float& a, float& b, float sred[2][8][2],
                                      int tid, int phase){
  for (int off = 32; off; off >>= 1){ a += __shfl_xor(a, off); b += __shfl_xor(b, off); }
  int pb = phase & 1;
  if ((tid & 63) == 0){ sred[pb][tid>>6][0] = a; sred[pb][tid>>6][1] = b; }
  __syncthreads();
  float sa = 0.f, sb = 0.f;
  #pragma unroll
  for (int w = 0; w < 8; w++){ sa += sred[pb][w][0]; sb += sred[pb][w][1]; }
  a = sa; b = sb;
}

__global__ __launch_bounds__(512) void k_fused(
    const float* __restrict__ x, const int* __restrict__ mask,
    const float* __restrict__ coords,
    const float* __restrict__ Wp, const float* __restrict__ bp,
    const float* __restrict__ Wq, const float* __restrict__ bq,
    const float* __restrict__ Wk, const float* __restrict__ bk,
    const float* __restrict__ Wv, const float* __restrict__ bv,
    const float* __restrict__ Wo, const float* __restrict__ bo,
    const float* __restrict__ g1, const float* __restrict__ b1,
    const float* __restrict__ g2, const float* __restrict__ b2,
    const float* __restrict__ W1, const float* __restrict__ bf1,
    const float* __restrict__ W2, const float* __restrict__ bfb2,
    float* __restrict__ out)
{
  __shared__ float sc_s[H_*L_];        // 27648 B scores
  __shared__ float is_s[L_];           // 3456  inv_std per key
  __shared__ float dc_s[3][L_];        // 10368 cached rel-coords (pass1 -> pass2)
  __shared__ float xh_s[N_][D_+1];     // 16512 centered rows, +1 pad: bank (n+e)%32
  __shared__ float ZU_s[H_][D_+4];     // 4224  u -> u*g1 -> ZZ, +4 pad: bank (4h+e)%32
  __shared__ float w_s[3][D_];         // centered Wp rows
  __shared__ float g1_s[D_], b1_s[D_], bp_s[D_];
  __shared__ float q_s[D_];
  __shared__ float hn_s[D_];
  __shared__ float qAxk_s[H_][N_];
  __shared__ float qGk_s[H_][3];
  __shared__ float S3_s[H_];
  __shared__ float varx_s[N_];
  __shared__ float dxp_s[N_][3];
  __shared__ int   mask_s[N_];
  __shared__ float cq_s[NC_][3];
  __shared__ float M6_s[6];
  __shared__ float mwp_s[3];
  __shared__ float Tnp_s[H_][2][N_];
  __shared__ float Sh_s[H_], RD_s[H_][3];
  __shared__ float att_s[D_], y_s[D_], f_s[DFF_];
  __shared__ float po[4][D_];
  __shared__ float sred[2][8][2];

  int bi = blockIdx.x;               // b*32+i
  int b = bi >> 5, i = bi & 31;
  int tid  = threadIdx.x;
  int wave = tid >> 6, lane = tid & 63;

  // ---- stage 0: small tensors + Wp centering + M6 ----
  if (tid < 384) w_s[tid>>7][tid&127] = Wp[tid];
  if (tid < D_){ g1_s[tid] = g1[tid]; b1_s[tid] = b1[tid]; bp_s[tid] = bp[tid]; }
  if (tid >= 384 && tid < 384+N_) mask_s[tid-384] = mask[b*N_ + (tid-384)];
  if (tid >= 416 && tid < 416+NC_*3){
    int t2 = tid - 416;
    cq_s[t2/3][t2%3] = coords[((size_t)(b*NC_ + t2/3)*N_ + i)*3 + t2%3];
  }
  __syncthreads();
  if (wave < 3){
    float s = w_s[wave][lane] + w_s[wave][lane+64];
    s = wave_red_sum(s);
    if (lane == 0) mwp_s[wave] = s*(1.f/D_);
  }
  __syncthreads();
  if (tid < 384) w_s[tid>>7][tid&127] -= mwp_s[tid>>7];
  __syncthreads();
  if (wave < 6){
    const int ja[6] = {0,0,0,1,1,2}, jb[6] = {0,1,2,1,2,2};
    float s = w_s[ja[wave]][lane]*w_s[jb[wave]][lane]
            + w_s[ja[wave]][lane+64]*w_s[jb[wave]][lane+64];
    s = wave_red_sum(s);
    if (lane == 0) M6_s[wave] = s;   // M00,M01,M02,M11,M12,M22
  }

  // ---- step 1: centered x rows + varx + dxp (each wave owns 4 rows) ----
  for (int r = wave; r < N_; r += 8){
    float t0 = x[((size_t)(b*N_+r))*D_ + lane]     + bp_s[lane];
    float t1 = x[((size_t)(b*N_+r))*D_ + lane+64]  + bp_s[lane+64];
    float mean = wave_red_sum(t0 + t1)*(1.f/D_);
    float xh0 = t0 - mean, xh1 = t1 - mean;
    xh_s[r][lane] = xh0; xh_s[r][lane+64] = xh1;
    float vv = xh0*xh0 + xh1*xh1;
    float d0 = xh0*w_s[0][lane] + xh1*w_s[0][lane+64];
    float d1 = xh0*w_s[1][lane] + xh1*w_s[1][lane+64];
    float d2 = xh0*w_s[2][lane] + xh1*w_s[2][lane+64];
    #pragma unroll
    for (int off = 32; off; off >>= 1){
      vv += __shfl_xor(vv, off); d0 += __shfl_xor(d0, off);
      d1 += __shfl_xor(d1, off); d2 += __shfl_xor(d2, off);
    }
    if (lane == 0){
      varx_s[r] = vv*(1.f/D_);
      dxp_s[r][0] = d0; dxp_s[r][1] = d1; dxp_s[r][2] = d2;
    }
  }
  __syncthreads();

  // ---- step 2: hn_i row, then q = hn_i @ Wq + bq ----
  if (tid < D_){
    float isq = rsqrtf(varx_s[i] + 1e-5f);
    hn_s[tid] = xh_s[i][tid]*isq*g1_s[tid] + b1_s[tid];
  }
  __syncthreads();
  {
    int slot = tid >> 7, d = tid & 127;
    float a = 0.f;
    #pragma unroll 8
    for (int e = slot*32; e < slot*32+32; e++) a += hn_s[e]*Wq[e*D_+d];
    po[slot][d] = a;
  }
  __syncthreads();
  if (tid < D_) q_s[tid] = po[0][tid]+po[1][tid]+po[2][tid]+po[3][tid] + bq[tid];
  __syncthreads();

  // ---- step 3: u_h[e] = Wk[e, h-slice]·q[h-slice]  (8 x 128) ----
  {
    int e = tid & 127, h0 = tid >> 7;            // h0 in 0..3, also h0+4
    #pragma unroll
    for (int hh = 0; hh < 2; hh++){
      int h = h0 + hh*4;
      const float4* wk4 = (const float4*)(Wk + (size_t)e*D_ + h*16);
      float s = 0.f;
      #pragma unroll
      for (int kq = 0; kq < 4; kq++){
        float4 wv4 = wk4[kq];
        s += wv4.x*q_s[h*16+kq*4+0] + wv4.y*q_s[h*16+kq*4+1]
           + wv4.z*q_s[h*16+kq*4+2] + wv4.w*q_s[h*16+kq*4+3];
      }
      ZU_s[h][e] = s;
    }
  }
  __syncthreads();
  // S3 + qGk from raw u (one wave per head)
  {
    int h = wave;
    float u0 = ZU_s[h][lane], u1 = ZU_s[h][lane+64];
    float s3 = b1_s[lane]*u0 + b1_s[lane+64]*u1;
    if (lane < 16) s3 += q_s[h*16+lane]*bk[h*16+lane];
    float qg0 = w_s[0][lane]*g1_s[lane]*u0 + w_s[0][lane+64]*g1_s[lane+64]*u1;
    float qg1 = w_s[1][lane]*g1_s[lane]*u0 + w_s[1][lane+64]*g1_s[lane+64]*u1;
    float qg2 = w_s[2][lane]*g1_s[lane]*u0 + w_s[2][lane+64]*g1_s[lane+64]*u1;
    #pragma unroll
    for (int off = 32; off; off >>= 1){
      s3  += __shfl_xor(s3,  off); qg0 += __shfl_xor(qg0, off);
      qg1 += __shfl_xor(qg1, off); qg2 += __shfl_xor(qg2, off);
    }
    if (lane == 0){ S3_s[h]=s3; qGk_s[h][0]=qg0; qGk_s[h][1]=qg1; qGk_s[h][2]=qg2; }
  }
  __syncthreads();
  // scale u by g1 in place -> ug
  {
    int e = tid & 127, h0 = tid >> 7;
    ZU_s[h0][e]   *= g1_s[e];
    ZU_s[h0+4][e] *= g1_s[e];
  }
  __syncthreads();
  // qAxk[h][n] = sum_e xh_n[e] * ug_h[e]  (512-way: e split in halves)
  {
    int half = tid >> 8, id = tid & 255, h = id >> 5, n = id & 31;
    float s = 0.f;
    #pragma unroll 8
    for (int e = half*64; e < half*64+64; e++) s += xh_s[n][e]*ZU_s[h][e];
    ((float*)po)[half*256 + id] = s;
  }
  __syncthreads();
  if (tid < 256){
    int h = tid >> 5, n = tid & 31;
    qAxk_s[h][n] = ((float*)po)[tid] + ((float*)po)[256 + tid];
  }
  __syncthreads();

  // ---- pass 1: inv_std + 8 head scores per key l=(c,n), cache dc ----
  for (int l = tid; l < L_; l += 512){
    int c = l >> 5, n = l & 31;
    const float* ck = coords + ((size_t)(b*NC_+c)*N_ + n)*3;
    float d0 = ck[0]-cq_s[c][0], d1 = ck[1]-cq_s[c][1], d2 = ck[2]-cq_s[c][2];
    dc_s[0][l] = d0; dc_s[1][l] = d1; dc_s[2][l] = d2;
    float quad = d0*d0*M6_s[0] + d1*d1*M6_s[3] + d2*d2*M6_s[5]
               + 2.f*(d0*d1*M6_s[1] + d0*d2*M6_s[2] + d1*d2*M6_s[4]);
    float lin  = d0*dxp_s[n][0] + d1*dxp_s[n][1] + d2*dxp_s[n][2];
    float E = varx_s[n] + (quad + 2.f*lin)*(1.f/D_);
    float is = rsqrtf(fmaxf(E, 0.f) + 1e-5f);
    is_s[l] = is;
    bool mk = mask_s[n] != 0;
    #pragma unroll
    for (int h = 0; h < H_; h++){
      float sc = 0.25f*(is*(qAxk_s[h][n]
                 + d0*qGk_s[h][0] + d1*qGk_s[h][1] + d2*qGk_s[h][2]) + S3_s[h]);
      sc_s[h*L_ + l] = mk ? sc : -1e9f;
    }
  }
  __syncthreads();

  // ---- pass 2: exact softmax, one wave per head ----
  {
    int h = tid >> 6, n = lane & 31, half = lane >> 5;
    int c0 = half ? 14 : 0, c1 = half ? NC_ : 14;
    float M = -3.0e38f;
    for (int c = c0; c < c1; c++) M = fmaxf(M, sc_s[h*L_ + c*N_ + n]);
    #pragma unroll
    for (int off = 32; off; off >>= 1) M = fmaxf(M, __shfl_xor(M, off));
    float S=0.f, Tn=0.f, r0=0.f, r1=0.f, r2=0.f;
    for (int c = c0; c < c1; c++){
      int l = c*N_ + n;
      float w = expf(sc_s[h*L_ + l] - M);
      float t = w * is_s[l];
      S += w; Tn += t;
      r0 += t*dc_s[0][l]; r1 += t*dc_s[1][l]; r2 += t*dc_s[2][l];
    }
    Tnp_s[h][half][n] = Tn;
    #pragma unroll
    for (int off = 32; off; off >>= 1){
      S  += __shfl_xor(S,  off);
      r0 += __shfl_xor(r0, off);
      r1 += __shfl_xor(r1, off);
      r2 += __shfl_xor(r2, off);
    }
    if (lane == 0){ Sh_s[h]=S; RD_s[h][0]=r0; RD_s[h][1]=r1; RD_s[h][2]=r2; }
  }
  __syncthreads();

  // ---- step 6: ZZ_h[e] = (sum_n Tn xh + sum_j RD_j w_j) g1 / S_h + b1 ----
  {
    int e = tid & 127, h0 = tid >> 7;
    #pragma unroll
    for (int hh = 0; hh < 2; hh++){
      int h = h0 + hh*4;
      float z = 0.f;
      #pragma unroll 8
      for (int n = 0; n < N_; n++){
        float Tn = Tnp_s[h][0][n] + Tnp_s[h][1][n];
        z += Tn * xh_s[n][e];
      }
      z += RD_s[h][0]*w_s[0][e] + RD_s[h][1]*w_s[1][e] + RD_s[h][2]*w_s[2][e];
      float rS = 1.f / fmaxf(Sh_s[h], 1e-30f);
      ZU_s[h][e] = z*g1_s[e]*rS + b1_s[e];
    }
  }
  __syncthreads();

  // ---- step 7: att_d = sum_e ZZ_{d>>4}[e] Wv[e][d] + bv[d] ----
  {
    int slot = tid >> 7, d = tid & 127, h = d >> 4;
    float a = 0.f;
    #pragma unroll 8
    for (int e = slot*32; e < slot*32+32; e++) a += ZU_s[h][e]*Wv[e*D_+d];
    po[slot][d] = a;
  }
  __syncthreads();
  if (tid < D_) att_s[tid] = po[0][tid]+po[1][tid]+po[2][tid]+po[3][tid] + bv[tid];
  __syncthreads();

  // ---- Wo + residual ----
  {
    int slot = tid >> 7, d = tid & 127;
    float a = 0.f;
    #pragma unroll 8
    for (int e = slot*32; e < slot*32+32; e++) a += att_s[e]*Wo[e*D_+d];
    po[slot][d] = a;
  }
  __syncthreads();
  float yv = 0.f;
  if (tid < D_){
    yv = x[(size_t)bi*D_+tid] + bp_s[tid] + bo[tid]
       + po[0][tid]+po[1][tid]+po[2][tid]+po[3][tid];
    y_s[tid] = yv;
  }
  // ---- LN2 ----
  float s1 = (tid < D_) ? yv : 0.f, dm = 0.f;
  bred2(s1, dm, sred, tid, 0);
  float dev = yv - s1*(1.f/D_);
  float v1 = (tid < D_) ? dev*dev : 0.f; dm = 0.f;
  bred2(v1, dm, sred, tid, 1);
  if (tid < D_) hn_s[tid] = dev*rsqrtf(v1*(1.f/D_)+1e-5f)*g2[tid] + b2[tid];
  __syncthreads();
  // ---- FFN ----
  float f = bf1[tid];
  #pragma unroll 8
  for (int e = 0; e < D_; e++) f += hn_s[e]*W1[e*DFF_+tid];
  f_s[tid] = fmaxf(f, 0.f);
  __syncthreads();
  {
    int slot = tid >> 7, d = tid & 127;
    float a = 0.f;
    #pragma unroll 8
    for (int j = slot*128; j < slot*128+128; j++) a += f_s[j]*W2[j*D_+d];
    po[slot][d] = a;
  }
  __syncthreads();
  if (tid < D_)
    out[(size_t)bi*D_+tid] = y_s[tid] + bfb2[tid]
                   + po[0][tid]+po[1][tid]+po[2][tid]+po[3][tid];
}

extern "C" void kernel_launch(void* const* d_in, const int* in_sizes, int n_in,
                              void* d_out, int out_size, void* d_ws, size_t ws_size,
                              hipStream_t stream){
  const float* x      = (const float*)d_in[0];
  const int*   mask   = (const int*)  d_in[1];
  const float* coords = (const float*)d_in[2];
  const float* Wp     = (const float*)d_in[3];
  const float* bp     = (const float*)d_in[4];
  const float* Wq     = (const float*)d_in[5];
  const float* bq     = (const float*)d_in[6];
  const float* Wk     = (const float*)d_in[7];
  const float* bk     = (const float*)d_in[8];
  const float* Wv     = (const float*)d_in[9];
  const float* bv     = (const float*)d_in[10];
  const float* Wo     = (const float*)d_in[11];
  const float* bo     = (const float*)d_in[12];
  const float* g1     = (const float*)d_in[13];
  const float* b1     = (const float*)d_in[14];
  const float* g2     = (const float*)d_in[15];
  const float* b2     = (const float*)d_in[16];
  const float* W1     = (const float*)d_in[17];
  const float* bf1    = (const float*)d_in[18];
  const float* W2     = (const float*)d_in[19];
  const float* bfb2   = (const float*)d_in[20];

  k_fused<<<B_*N_, 512, 0, stream>>>(x, mask, coords, Wp, bp, Wq, bq, Wk, bk,
                                     Wv, bv, Wo, bo, g1, b1, g2, b2,
                                     W1, bf1, W2, bfb2, (float*)d_out);
}

// Round 2
// 117.591 us; speedup vs baseline: 1.0683x; 1.0683x over previous
//
#include <hip/hip_runtime.h>

// AtomEncoderLayer fused single-kernel, latency-optimized: B=4, N=32, D=128,
// H=8, NC=27, DK=16, DFF=512, L=864. One block per (b,i), 1024 threads
// (16 waves). All long loops split across 2-8x more threads than the 512-thread
// version; barrier count cut to ~19; all bias/small vectors staged up front.
// Algebra identical to previous verified version:
//   u_h[e]     = Wk[e, h-slice]·q[h-slice]
//   qAxk[h][n] = sum_e xg_n[e] u_h[e]           (xg = centered-x * g1)
//   qGk[h][j]  = sum_e wcg_j[e] u_h[e]          (wcg = centered-Wp * g1)
//   S3[h]      = q·bk|_h + sum_e b1[e] u_h[e]
//   dxp uses RAW Wp rows (sum xh = 0), M6 via M_ab = P_ab - D ma mb.
//   ZZ_h[e]    = (sum_n Tn xg + sum_j RD_j wcg_j)/S_h + b1[e]
//   att_d      = sum_e ZZ_h[e] Wv[e][d] + bv[d]

#define B_ 4
#define N_ 32
#define D_ 128
#define H_ 8
#define NC_ 27
#define DFF_ 512
#define L_ (NC_*N_)        // 864

__device__ __forceinline__ float wred(float v){
  #pragma unroll
  for (int off = 32; off; off >>= 1) v += __shfl_xor(v, off);
  return v;
}

__global__ __launch_bounds__(1024) void k_fused(
    const float* __restrict__ x, const int* __restrict__ mask,
    const float* __restrict__ coords,
    const float* __restrict__ Wp, const float* __restrict__ bp,
    const float* __restrict__ Wq, const float* __restrict__ bq,
    const float* __restrict__ Wk, const float* __restrict__ bk,
    const float* __restrict__ Wv, const float* __restrict__ bv,
    const float* __restrict__ Wo, const float* __restrict__ bo,
    const float* __restrict__ g1, const float* __restrict__ b1,
    const float* __restrict__ g2, const float* __restrict__ b2,
    const float* __restrict__ W1, const float* __restrict__ bf1,
    const float* __restrict__ W2, const float* __restrict__ bfb2,
    float* __restrict__ out)
{
  __shared__ float sc_s[H_*L_];        // 27648 B scores
  __shared__ float is_s[L_];           // inv_std per key
  __shared__ float dc_s[3][L_];        // rel-coords cache
  __shared__ float xg_s[N_][D_+1];     // centered x * g1; +1 pad: bank (n+e)%32
  __shared__ float zz_s[H_][D_+1];     // u_h then ZZ_h; +1 pad
  __shared__ float w_s[3][D_];         // raw Wp rows
  __shared__ float wcg_s[3][D_];       // centered Wp * g1
  __shared__ float g1_s[D_], b1_s[D_], bp_s[D_], bq_s[D_], bk_s[D_];
  __shared__ float g2_s[D_], b2_s[D_], bv_s[D_], bo_s[D_], bfb2_s[D_];
  __shared__ float q_s[D_], hn_s[D_], hn2_s[D_], att_s[D_], y_s[D_];
  __shared__ float qAxk_s[H_][N_];
  __shared__ float qGk_s[H_][3];
  __shared__ float S3_s[H_];
  __shared__ float varx_s[N_];
  __shared__ float dxp_s[N_][3];
  __shared__ int   mask_s[N_];
  __shared__ float cq_s[NC_][3];
  __shared__ float M6_s[6], mwp_s[3], P6_s[6];
  __shared__ float pmax_s[H_][2];
  __shared__ float Tnp_s[H_][2][N_];
  __shared__ float Sp_s[H_][2], RDp_s[H_][2][3];
  __shared__ float f_s[DFF_];
  __shared__ float po[8][D_];          // partial buffer, also flat [1024]

  int bi = blockIdx.x;                 // b*32+i
  int b = bi >> 5, i = bi & 31;
  int tid = threadIdx.x, wave = tid >> 6, lane = tid & 63;

  // ---- phase 0: issue all independent global loads + stage small vectors ----
  int r0 = wave*2, r1 = wave*2+1;      // each wave owns 2 rows
  float xa0 = x[(size_t)(b*N_+r0)*D_ + lane];
  float xa1 = x[(size_t)(b*N_+r0)*D_ + lane+64];
  float xb0 = x[(size_t)(b*N_+r1)*D_ + lane];
  float xb1 = x[(size_t)(b*N_+r1)*D_ + lane+64];
  float xi0 = 0.f, xi1 = 0.f;
  if (wave == 0){ xi0 = x[(size_t)bi*D_+lane]; xi1 = x[(size_t)bi*D_+lane+64]; }
  float ck0=0.f, ck1=0.f, ck2=0.f;
  if (tid < L_){
    int c = tid >> 5, n = tid & 31;
    const float* ck = coords + ((size_t)(b*NC_+c)*N_ + n)*3;
    ck0 = ck[0]; ck1 = ck[1]; ck2 = ck[2];
  }
  if (tid < 384) w_s[tid>>7][tid&127] = Wp[tid];
  if (tid < 128)                g2_s[tid]       = g2[tid];
  else if (tid < 256)           b2_s[tid-128]   = b2[tid-128];
  else if (tid < 384)           bv_s[tid-256]   = bv[tid-256];
  else if (tid < 512){ int t=tid-384; g1_s[t]=g1[t]; bo_s[t]=bo[t]; }
  else if (tid < 640){ int t=tid-512; b1_s[t]=b1[t]; bfb2_s[t]=bfb2[t]; }
  else if (tid < 768){ int t=tid-640; bp_s[t]=bp[t]; bq_s[t]=bq[t]; }
  else if (tid < 800)           mask_s[tid-768] = mask[b*N_ + (tid-768)];
  else if (tid < 881){
    int t = tid-800;
    cq_s[t/3][t%3] = coords[((size_t)(b*NC_ + t/3)*N_ + i)*3 + t%3];
  }
  else if (tid < 1009)          bk_s[tid-881]   = bk[tid-881];
  __syncthreads();   // B1

  // ---- phase 1: rows (xh,varx,dxp), dc, Wp means + raw products ----
  {
    // row r0
    float t0 = xa0 + bp_s[lane], t1 = xa1 + bp_s[lane+64];
    float mean = wred(t0+t1)*(1.f/D_);
    float h0 = t0-mean, h1 = t1-mean;
    xg_s[r0][lane]    = h0*g1_s[lane];
    xg_s[r0][lane+64] = h1*g1_s[lane+64];
    float vv = h0*h0 + h1*h1;
    float d0 = h0*w_s[0][lane] + h1*w_s[0][lane+64];
    float d1 = h0*w_s[1][lane] + h1*w_s[1][lane+64];
    float d2 = h0*w_s[2][lane] + h1*w_s[2][lane+64];
    #pragma unroll
    for (int off=32; off; off>>=1){
      vv += __shfl_xor(vv,off); d0 += __shfl_xor(d0,off);
      d1 += __shfl_xor(d1,off); d2 += __shfl_xor(d2,off);
    }
    if (lane==0){ varx_s[r0]=vv*(1.f/D_);
      dxp_s[r0][0]=d0; dxp_s[r0][1]=d1; dxp_s[r0][2]=d2; }
    // row r1
    t0 = xb0 + bp_s[lane]; t1 = xb1 + bp_s[lane+64];
    mean = wred(t0+t1)*(1.f/D_);
    h0 = t0-mean; h1 = t1-mean;
    xg_s[r1][lane]    = h0*g1_s[lane];
    xg_s[r1][lane+64] = h1*g1_s[lane+64];
    vv = h0*h0 + h1*h1;
    d0 = h0*w_s[0][lane] + h1*w_s[0][lane+64];
    d1 = h0*w_s[1][lane] + h1*w_s[1][lane+64];
    d2 = h0*w_s[2][lane] + h1*w_s[2][lane+64];
    #pragma unroll
    for (int off=32; off; off>>=1){
      vv += __shfl_xor(vv,off); d0 += __shfl_xor(d0,off);
      d1 += __shfl_xor(d1,off); d2 += __shfl_xor(d2,off);
    }
    if (lane==0){ varx_s[r1]=vv*(1.f/D_);
      dxp_s[r1][0]=d0; dxp_s[r1][1]=d1; dxp_s[r1][2]=d2; }
  }
  float dc0=0.f, dc1=0.f, dc2=0.f;
  if (tid < L_){
    int c = tid >> 5;
    dc0 = ck0 - cq_s[c][0]; dc1 = ck1 - cq_s[c][1]; dc2 = ck2 - cq_s[c][2];
    dc_s[0][tid]=dc0; dc_s[1][tid]=dc1; dc_s[2][tid]=dc2;
  }
  if (wave >= 8 && wave < 11){          // Wp row means
    int j = wave - 8;
    float s = w_s[j][lane] + w_s[j][lane+64];
    s = wred(s);
    if (lane==0) mwp_s[j] = s*(1.f/D_);
  }
  if (wave >= 10){                      // raw products P_ab (waves 10..15)
    int idx = wave - 10;
    int ja = (idx>=3) + (idx>=5);
    int jb = idx - (idx>=3)*2 - (idx>=5);
    float s = w_s[ja][lane]*w_s[jb][lane] + w_s[ja][lane+64]*w_s[jb][lane+64];
    s = wred(s);
    if (lane==0) P6_s[idx] = s;
  }
  __syncthreads();   // B2

  // ---- phase 2: wcg, M6 finalize, hn_i ----
  if (tid < 384){ int j=tid>>7, e=tid&127;
    wcg_s[j][e] = (w_s[j][e] - mwp_s[j])*g1_s[e]; }
  if (tid == 384){
    M6_s[0]=P6_s[0]-D_*mwp_s[0]*mwp_s[0];
    M6_s[1]=P6_s[1]-D_*mwp_s[0]*mwp_s[1];
    M6_s[2]=P6_s[2]-D_*mwp_s[0]*mwp_s[2];
    M6_s[3]=P6_s[3]-D_*mwp_s[1]*mwp_s[1];
    M6_s[4]=P6_s[4]-D_*mwp_s[1]*mwp_s[2];
    M6_s[5]=P6_s[5]-D_*mwp_s[2]*mwp_s[2];
  }
  if (tid >= 512 && tid < 640){ int e = tid-512;
    hn_s[e] = xg_s[i][e]*rsqrtf(varx_s[i]+1e-5f) + b1_s[e]; }
  __syncthreads();   // B3

  // ---- phase 3: q partials (8 slots x 16 e) ----
  {
    int slot = tid>>7, d = tid&127;
    float a = 0.f;
    #pragma unroll
    for (int e = slot*16; e < slot*16+16; e++) a += hn_s[e]*Wq[e*D_+d];
    po[slot][d] = a;
  }
  __syncthreads();   // B4

  // ---- phase 4: q combine ----
  if (tid < D_){
    float a = bq_s[tid];
    #pragma unroll
    for (int s=0;s<8;s++) a += po[s][tid];
    q_s[tid] = a;
  }
  __syncthreads();   // B5

  // ---- phase 5: u_h[e] (1024 = 8h x 128e) ----
  {
    int h = tid>>7, e = tid&127;
    const float4* wk4 = (const float4*)(Wk + (size_t)e*D_ + h*16);
    float s = 0.f;
    #pragma unroll
    for (int kq=0; kq<4; kq++){
      float4 w4 = wk4[kq];
      s += w4.x*q_s[h*16+kq*4+0] + w4.y*q_s[h*16+kq*4+1]
         + w4.z*q_s[h*16+kq*4+2] + w4.w*q_s[h*16+kq*4+3];
    }
    zz_s[h][e] = s;                    // raw u
  }
  __syncthreads();   // B6

  // ---- phase 6: qAxk partials (4 e-quarters x 256 (h,n)) ----
  {
    int quarter = tid>>8, id = tid&255, h = id>>5, n = id&31;
    float s = 0.f;
    #pragma unroll 8
    for (int e = quarter*32; e < quarter*32+32; e++) s += xg_s[n][e]*zz_s[h][e];
    ((float*)po)[quarter*256 + id] = s;
  }
  __syncthreads();   // B7

  // ---- phase 7: qAxk combine + S3/qGk (one wave per head) ----
  if (tid < 256){
    int h = tid>>5, n = tid&31;
    qAxk_s[h][n] = ((float*)po)[tid] + ((float*)po)[256+tid]
                 + ((float*)po)[512+tid] + ((float*)po)[768+tid];
  }
  if (wave >= 8){
    int h = wave - 8;
    float u0 = zz_s[h][lane], u1 = zz_s[h][lane+64];
    float s3 = b1_s[lane]*u0 + b1_s[lane+64]*u1;
    if (lane < 16) s3 += q_s[h*16+lane]*bk_s[h*16+lane];
    float qg0 = wcg_s[0][lane]*u0 + wcg_s[0][lane+64]*u1;
    float qg1 = wcg_s[1][lane]*u0 + wcg_s[1][lane+64]*u1;
    float qg2 = wcg_s[2][lane]*u0 + wcg_s[2][lane+64]*u1;
    #pragma unroll
    for (int off=32; off; off>>=1){
      s3  += __shfl_xor(s3,off);  qg0 += __shfl_xor(qg0,off);
      qg1 += __shfl_xor(qg1,off); qg2 += __shfl_xor(qg2,off);
    }
    if (lane==0){ S3_s[h]=s3; qGk_s[h][0]=qg0; qGk_s[h][1]=qg1; qGk_s[h][2]=qg2; }
  }
  __syncthreads();   // B8

  // ---- phase 8: pass1 — is + 8 head scores per key (1 iter, tid<864) ----
  if (tid < L_){
    int n = tid & 31;
    float quad = dc0*dc0*M6_s[0] + dc1*dc1*M6_s[3] + dc2*dc2*M6_s[5]
               + 2.f*(dc0*dc1*M6_s[1] + dc0*dc2*M6_s[2] + dc1*dc2*M6_s[4]);
    float lin  = dc0*dxp_s[n][0] + dc1*dxp_s[n][1] + dc2*dxp_s[n][2];
    float E = varx_s[n] + (quad + 2.f*lin)*(1.f/D_);
    float is = rsqrtf(fmaxf(E, 0.f) + 1e-5f);
    is_s[tid] = is;
    bool mk = mask_s[n] != 0;
    #pragma unroll
    for (int h=0; h<H_; h++){
      float sc = 0.25f*(is*(qAxk_s[h][n]
               + dc0*qGk_s[h][0] + dc1*qGk_s[h][1] + dc2*qGk_s[h][2]) + S3_s[h]);
      sc_s[h*L_ + tid] = mk ? sc : -1e9f;
    }
  }
  __syncthreads();   // B9

  // ---- phase 9: per-head max (2 waves/head, quarter ranges) ----
  int h2 = wave>>1, sub = wave&1, n2 = lane&31, half2 = lane>>5;
  int q4 = sub*2 + half2, c0 = q4*7, c1 = (q4==3) ? NC_ : c0+7;
  {
    float M = -3.0e38f;
    for (int c=c0; c<c1; c++) M = fmaxf(M, sc_s[h2*L_ + c*N_ + n2]);
    #pragma unroll
    for (int off=32; off; off>>=1) M = fmaxf(M, __shfl_xor(M, off));
    if (lane==0) pmax_s[h2][sub] = M;
  }
  __syncthreads();   // B10

  // ---- phase 10: exp + partial sums ----
  {
    float M = fmaxf(pmax_s[h2][0], pmax_s[h2][1]);
    float S=0.f, Tn=0.f, rr0=0.f, rr1=0.f, rr2=0.f;
    for (int c=c0; c<c1; c++){
      int l = c*N_ + n2;
      float w_ = __expf(sc_s[h2*L_ + l] - M);
      float t = w_ * is_s[l];
      S += w_; Tn += t;
      rr0 += t*dc_s[0][l]; rr1 += t*dc_s[1][l]; rr2 += t*dc_s[2][l];
    }
    float Tn2 = Tn + __shfl_xor(Tn, 32);     // combine the 2 lane-halves (same n)
    if (lane < 32) Tnp_s[h2][sub][lane] = Tn2;
    #pragma unroll
    for (int off=32; off; off>>=1){
      S   += __shfl_xor(S,off);   rr0 += __shfl_xor(rr0,off);
      rr1 += __shfl_xor(rr1,off); rr2 += __shfl_xor(rr2,off);
    }
    if (lane==0){ Sp_s[h2][sub]=S;
      RDp_s[h2][sub][0]=rr0; RDp_s[h2][sub][1]=rr1; RDp_s[h2][sub][2]=rr2; }
  }
  __syncthreads();   // B11

  // ---- phase 11: ZZ_h[e] (1024 = 8h x 128e) ----
  {
    int h = tid>>7, e = tid&127;
    float rS = 1.f / fmaxf(Sp_s[h][0]+Sp_s[h][1], 1e-30f);
    float z = 0.f;
    #pragma unroll 8
    for (int n=0; n<N_; n++){
      float Tn = Tnp_s[h][0][n] + Tnp_s[h][1][n];
      z += Tn * xg_s[n][e];
    }
    float R0 = RDp_s[h][0][0]+RDp_s[h][1][0];
    float R1 = RDp_s[h][0][1]+RDp_s[h][1][1];
    float R2 = RDp_s[h][0][2]+RDp_s[h][1][2];
    z += R0*wcg_s[0][e] + R1*wcg_s[1][e] + R2*wcg_s[2][e];
    zz_s[h][e] = z*rS + b1_s[e];
  }
  __syncthreads();   // B12

  // ---- phase 12: Wv partials (8 slots x 16 e) ----
  {
    int slot = tid>>7, d = tid&127, h = d>>4;
    float a = 0.f;
    #pragma unroll
    for (int e = slot*16; e < slot*16+16; e++) a += zz_s[h][e]*Wv[e*D_+d];
    po[slot][d] = a;
  }
  __syncthreads();   // B13

  // ---- phase 13: att combine ----
  if (tid < D_){
    float a = bv_s[tid];
    #pragma unroll
    for (int s=0;s<8;s++) a += po[s][tid];
    att_s[tid] = a;
  }
  __syncthreads();   // B14

  // ---- phase 14: Wo partials ----
  {
    int slot = tid>>7, d = tid&127;
    float a = 0.f;
    #pragma unroll
    for (int e = slot*16; e < slot*16+16; e++) a += att_s[e]*Wo[e*D_+d];
    po[slot][d] = a;
  }
  __syncthreads();   // B15

  // ---- phase 15: y + LN2 entirely in wave 0 (no extra barriers) ----
  if (wave == 0){
    float y0 = xi0 + bp_s[lane]    + bo_s[lane];
    float y1 = xi1 + bp_s[lane+64] + bo_s[lane+64];
    #pragma unroll
    for (int s=0;s<8;s++){ y0 += po[s][lane]; y1 += po[s][lane+64]; }
    y_s[lane] = y0; y_s[lane+64] = y1;
    float mean = wred(y0+y1)*(1.f/D_);
    float v0 = y0-mean, v1 = y1-mean;
    float var = wred(v0*v0+v1*v1)*(1.f/D_);
    float isd = rsqrtf(var + 1e-5f);
    hn2_s[lane]    = v0*isd*g2_s[lane]    + b2_s[lane];
    hn2_s[lane+64] = v1*isd*g2_s[lane+64] + b2_s[lane+64];
  }
  __syncthreads();   // B16

  // ---- phase 16: FFN1 partials (512 cols x 2 e-halves) ----
  {
    int col = tid&511, half = tid>>9;
    float a = half ? 0.f : bf1[col];
    #pragma unroll 16
    for (int e = half*64; e < half*64+64; e++)
      a += hn2_s[e]*W1[(size_t)e*DFF_ + col];
    ((float*)po)[tid] = a;
  }
  __syncthreads();   // B17

  // ---- phase 17: relu combine ----
  if (tid < DFF_)
    f_s[tid] = fmaxf(((float*)po)[tid] + ((float*)po)[DFF_+tid], 0.f);
  __syncthreads();   // B18

  // ---- phase 18: FFN2 partials (8 slots x 64 j) ----
  {
    int slot = tid>>7, d = tid&127;
    float a = 0.f;
    #pragma unroll 16
    for (int j = slot*64; j < slot*64+64; j++)
      a += f_s[j]*W2[(size_t)j*D_ + d];
    po[slot][d] = a;
  }
  __syncthreads();   // B19

  // ---- phase 19: out ----
  if (tid < D_){
    float a = y_s[tid] + bfb2_s[tid];
    #pragma unroll
    for (int s=0;s<8;s++) a += po[s][tid];
    out[(size_t)bi*D_ + tid] = a;
  }
}

extern "C" void kernel_launch(void* const* d_in, const int* in_sizes, int n_in,
                              void* d_out, int out_size, void* d_ws, size_t ws_size,
                              hipStream_t stream){
  const float* x      = (const float*)d_in[0];
  const int*   mask   = (const int*)  d_in[1];
  const float* coords = (const float*)d_in[2];
  const float* Wp     = (const float*)d_in[3];
  const float* bp     = (const float*)d_in[4];
  const float* Wq     = (const float*)d_in[5];
  const float* bq     = (const float*)d_in[6];
  const float* Wk     = (const float*)d_in[7];
  const float* bk     = (const float*)d_in[8];
  const float* Wv     = (const float*)d_in[9];
  const float* bv     = (const float*)d_in[10];
  const float* Wo     = (const float*)d_in[11];
  const float* bo     = (const float*)d_in[12];
  const float* g1     = (const float*)d_in[13];
  const float* b1     = (const float*)d_in[14];
  const float* g2     = (const float*)d_in[15];
  const float* b2     = (const float*)d_in[16];
  const float* W1     = (const float*)d_in[17];
  const float* bf1    = (const float*)d_in[18];
  const float* W2     = (const float*)d_in[19];
  const float* bfb2   = (const float*)d_in[20];

  k_fused<<<B_*N_, 1024, 0, stream>>>(x, mask, coords, Wp, bp, Wq, bq, Wk, bk,
                                      Wv, bv, Wo, bo, g1, b1, g2, b2,
                                      W1, bf1, W2, bfb2, (float*)d_out);
}

// Round 3
// 112.652 us; speedup vs baseline: 1.1152x; 1.0438x over previous
//
#include <hip/hip_runtime.h>

// AtomEncoderLayer fused single-kernel, round 3: latency-chain attack.
// B=4, N=32, D=128, H=8, NC=27, DK=16, DFF=512, L=864.
// One block per (b,i), 1024 threads (16 waves), 18 barriers.
// New vs round 2:
//  - all weight tiles register-PREFETCHED one phase early (addresses are
//    data-independent; the vmcnt(0) drain at the next barrier is the wait,
//    hidden under the preceding phase's compute)
//  - float4 weight loads (4x fewer issues): Wq/Wv/Wo as 32 e-slots x 32
//    d4-groups, W1/W2 as 16 float4 per thread
//  - scores held in registers (sc_s LDS array + its barrier eliminated);
//    is_s computation hoisted to phase 2 (local M6 recompute)
// Algebra identical to the round-2 verified version.

#define B_ 4
#define N_ 32
#define D_ 128
#define H_ 8
#define NC_ 27
#define DFF_ 512
#define L_ (NC_*N_)        // 864

__device__ __forceinline__ float wred(float v){
  #pragma unroll
  for (int off = 32; off; off >>= 1) v += __shfl_xor(v, off);
  return v;
}

__global__ __launch_bounds__(1024) void k_fused(
    const float* __restrict__ x, const int* __restrict__ mask,
    const float* __restrict__ coords,
    const float* __restrict__ Wp, const float* __restrict__ bp,
    const float* __restrict__ Wq, const float* __restrict__ bq,
    const float* __restrict__ Wk, const float* __restrict__ bk,
    const float* __restrict__ Wv, const float* __restrict__ bv,
    const float* __restrict__ Wo, const float* __restrict__ bo,
    const float* __restrict__ g1, const float* __restrict__ b1,
    const float* __restrict__ g2, const float* __restrict__ b2,
    const float* __restrict__ W1, const float* __restrict__ bf1,
    const float* __restrict__ W2, const float* __restrict__ bfb2,
    float* __restrict__ out)
{
  __shared__ float is_s[L_];           // inv_std per key
  __shared__ float dc_s[3][L_];        // rel-coords cache
  __shared__ float xg_s[N_][D_+1];     // centered x * g1; +1 pad
  __shared__ float zz_s[H_][D_+1];     // u_h then ZZ_h; +1 pad
  __shared__ float w_s[3][D_];         // raw Wp rows
  __shared__ float wcg_s[3][D_];       // centered Wp * g1
  __shared__ float g1_s[D_], b1_s[D_], bp_s[D_], bq_s[D_], bk_s[D_];
  __shared__ float g2_s[D_], b2_s[D_], bv_s[D_], bo_s[D_], bfb2_s[D_];
  __shared__ float bf1_s[DFF_];
  __shared__ float q_s[D_], hn_s[D_], hn2_s[D_], att_s[D_], y_s[D_];
  __shared__ float qAxk_s[H_][N_];
  __shared__ float qGk_s[H_][3];
  __shared__ float S3_s[H_];
  __shared__ float varx_s[N_];
  __shared__ float dxp_s[N_][3];
  __shared__ int   mask_s[N_];
  __shared__ float cq_s[NC_][3];
  __shared__ float mwp_s[3], P6_s[6];
  __shared__ float pmax_s[H_][2];
  __shared__ float Tnp_s[H_][2][N_];
  __shared__ float Sp_s[H_][2], RDp_s[H_][2][3];
  __shared__ float f_s[DFF_];
  __shared__ float pf_s[4096];         // 16KB partial buffer, multi-shape
  float4* pf4 = (float4*)pf_s;

  int bi = blockIdx.x;                 // b*32+i
  int b = bi >> 5, i = bi & 31;
  int tid = threadIdx.x, wave = tid >> 6, lane = tid & 63;
  int es = tid >> 5, d4 = tid & 31;    // 32 e-slots x 32 d4 mapping

  // ================= phase 0: stage + prefetch Wq/Wk ==================
  int r0 = wave*2, r1 = wave*2+1;
  float xa0 = x[(size_t)(b*N_+r0)*D_ + lane];
  float xa1 = x[(size_t)(b*N_+r0)*D_ + lane+64];
  float xb0 = x[(size_t)(b*N_+r1)*D_ + lane];
  float xb1 = x[(size_t)(b*N_+r1)*D_ + lane+64];
  float xi0 = 0.f, xi1 = 0.f;
  if (wave == 0){ xi0 = x[(size_t)bi*D_+lane]; xi1 = x[(size_t)bi*D_+lane+64]; }
  float ck0=0.f, ck1=0.f, ck2=0.f;
  if (tid < L_){
    int c = tid >> 5, n = tid & 31;
    const float* ck = coords + ((size_t)(b*NC_+c)*N_ + n)*3;
    ck0 = ck[0]; ck1 = ck[1]; ck2 = ck[2];
  }
  // prefetch Wq tile for phase 3 (es,d4): rows es*4..+3, cols d4*4..+3
  float4 wq4[4];
  #pragma unroll
  for (int k=0;k<4;k++)
    wq4[k] = *(const float4*)(Wq + (size_t)(es*4+k)*D_ + d4*4);
  // prefetch Wk tile for phase 5 (h=tid>>7, e=tid&127): cols h*16..+15
  float4 wk4[4];
  {
    int h = tid>>7, e = tid&127;
    #pragma unroll
    for (int k=0;k<4;k++)
      wk4[k] = *(const float4*)(Wk + (size_t)e*D_ + h*16 + k*4);
  }
  if (tid < 384) w_s[tid>>7][tid&127] = Wp[tid];
  if      (tid < 128)  g1_s[tid]      = g1[tid];
  else if (tid < 256)  b1_s[tid-128]  = b1[tid-128];
  else if (tid < 384)  bp_s[tid-256]  = bp[tid-256];
  else if (tid < 512)  bq_s[tid-384]  = bq[tid-384];
  else if (tid < 640)  bk_s[tid-512]  = bk[tid-512];
  else if (tid < 768)  g2_s[tid-640]  = g2[tid-640];
  else if (tid < 896)  b2_s[tid-768]  = b2[tid-768];
  else                 bv_s[tid-896]  = bv[tid-896];
  if      (tid < 128)  bo_s[tid]      = bo[tid];
  else if (tid < 256)  bfb2_s[tid-128]= bfb2[tid-128];
  else if (tid < 768)  bf1_s[tid-256] = bf1[tid-256];
  else if (tid < 800)  mask_s[tid-768]= mask[b*N_ + (tid-768)];
  else if (tid < 881){
    int t = tid-800;
    cq_s[t/3][t%3] = coords[((size_t)(b*NC_ + t/3)*N_ + i)*3 + t%3];
  }
  __syncthreads();   // B1

  // ========= phase 1: rows (xg,varx,dxp), dc, Wp means + P6 ===========
  {
    float t0 = xa0 + bp_s[lane], t1 = xa1 + bp_s[lane+64];
    float mean = wred(t0+t1)*(1.f/D_);
    float h0 = t0-mean, h1 = t1-mean;
    xg_s[r0][lane]    = h0*g1_s[lane];
    xg_s[r0][lane+64] = h1*g1_s[lane+64];
    float vv = h0*h0 + h1*h1;
    float d0 = h0*w_s[0][lane] + h1*w_s[0][lane+64];
    float d1 = h0*w_s[1][lane] + h1*w_s[1][lane+64];
    float d2 = h0*w_s[2][lane] + h1*w_s[2][lane+64];
    #pragma unroll
    for (int off=32; off; off>>=1){
      vv += __shfl_xor(vv,off); d0 += __shfl_xor(d0,off);
      d1 += __shfl_xor(d1,off); d2 += __shfl_xor(d2,off);
    }
    if (lane==0){ varx_s[r0]=vv*(1.f/D_);
      dxp_s[r0][0]=d0; dxp_s[r0][1]=d1; dxp_s[r0][2]=d2; }
    t0 = xb0 + bp_s[lane]; t1 = xb1 + bp_s[lane+64];
    mean = wred(t0+t1)*(1.f/D_);
    h0 = t0-mean; h1 = t1-mean;
    xg_s[r1][lane]    = h0*g1_s[lane];
    xg_s[r1][lane+64] = h1*g1_s[lane+64];
    vv = h0*h0 + h1*h1;
    d0 = h0*w_s[0][lane] + h1*w_s[0][lane+64];
    d1 = h0*w_s[1][lane] + h1*w_s[1][lane+64];
    d2 = h0*w_s[2][lane] + h1*w_s[2][lane+64];
    #pragma unroll
    for (int off=32; off; off>>=1){
      vv += __shfl_xor(vv,off); d0 += __shfl_xor(d0,off);
      d1 += __shfl_xor(d1,off); d2 += __shfl_xor(d2,off);
    }
    if (lane==0){ varx_s[r1]=vv*(1.f/D_);
      dxp_s[r1][0]=d0; dxp_s[r1][1]=d1; dxp_s[r1][2]=d2; }
  }
  float dc0=0.f, dc1=0.f, dc2=0.f;
  if (tid < L_){
    int c = tid >> 5;
    dc0 = ck0 - cq_s[c][0]; dc1 = ck1 - cq_s[c][1]; dc2 = ck2 - cq_s[c][2];
    dc_s[0][tid]=dc0; dc_s[1][tid]=dc1; dc_s[2][tid]=dc2;
  }
  if (wave >= 8 && wave < 11){
    int j = wave - 8;
    float s = w_s[j][lane] + w_s[j][lane+64];
    s = wred(s);
    if (lane==0) mwp_s[j] = s*(1.f/D_);
  }
  if (wave >= 10){
    int idx = wave - 10;
    int ja = (idx>=3) + (idx>=5);
    int jb = idx - (idx>=3)*2 - (idx>=5);
    float s = w_s[ja][lane]*w_s[jb][lane] + w_s[ja][lane+64]*w_s[jb][lane+64];
    s = wred(s);
    if (lane==0) P6_s[idx] = s;
  }
  __syncthreads();   // B2

  // ========= phase 2: is_s (hoisted), wcg, hn_i ===========
  if (tid < L_){
    int n = tid & 31;
    float m0 = mwp_s[0], m1 = mwp_s[1], m2 = mwp_s[2];
    float M00 = P6_s[0]-D_*m0*m0, M01 = P6_s[1]-D_*m0*m1;
    float M02 = P6_s[2]-D_*m0*m2, M11 = P6_s[3]-D_*m1*m1;
    float M12 = P6_s[4]-D_*m1*m2, M22 = P6_s[5]-D_*m2*m2;
    float quad = dc0*dc0*M00 + dc1*dc1*M11 + dc2*dc2*M22
               + 2.f*(dc0*dc1*M01 + dc0*dc2*M02 + dc1*dc2*M12);
    float lin  = dc0*dxp_s[n][0] + dc1*dxp_s[n][1] + dc2*dxp_s[n][2];
    float E = varx_s[n] + (quad + 2.f*lin)*(1.f/D_);
    is_s[tid] = rsqrtf(fmaxf(E, 0.f) + 1e-5f);
  }
  if (tid < 384){ int j=tid>>7, e=tid&127;
    wcg_s[j][e] = (w_s[j][e] - mwp_s[j])*g1_s[e]; }
  if (tid >= 896){ int e = tid-896;
    hn_s[e] = xg_s[i][e]*rsqrtf(varx_s[i]+1e-5f) + b1_s[e]; }
  __syncthreads();   // B3

  // ========= phase 3: q partials, prefetched Wq (32 es x 32 d4) =========
  {
    float4 acc = {0.f,0.f,0.f,0.f};
    #pragma unroll
    for (int k=0;k<4;k++){
      float h = hn_s[es*4+k];
      acc.x += h*wq4[k].x; acc.y += h*wq4[k].y;
      acc.z += h*wq4[k].z; acc.w += h*wq4[k].w;
    }
    pf4[es*32 + d4] = acc;
  }
  __syncthreads();   // B4

  // ========= phase 4: q combine =========
  if (tid < D_){
    float a = bq_s[tid];
    #pragma unroll
    for (int s=0;s<32;s++) a += pf_s[s*D_+tid];
    q_s[tid] = a;
  }
  __syncthreads();   // B5

  // ========= phase 5: u_h[e], prefetched Wk (8h x 128e) =========
  {
    int h = tid>>7, e = tid&127;
    float s = 0.f;
    #pragma unroll
    for (int kq=0; kq<4; kq++){
      s += wk4[kq].x*q_s[h*16+kq*4+0] + wk4[kq].y*q_s[h*16+kq*4+1]
         + wk4[kq].z*q_s[h*16+kq*4+2] + wk4[kq].w*q_s[h*16+kq*4+3];
    }
    zz_s[h][e] = s;                    // raw u
  }
  __syncthreads();   // B6

  // ========= phase 6: qAxk partials (4 e-quarters x 256 (h,n)) =========
  {
    int quarter = tid>>8, id = tid&255, h = id>>5, n = id&31;
    float s = 0.f;
    #pragma unroll 8
    for (int e = quarter*32; e < quarter*32+32; e++) s += xg_s[n][e]*zz_s[h][e];
    pf_s[quarter*256 + id] = s;
  }
  __syncthreads();   // B7

  // ========= phase 7: qAxk combine + S3/qGk =========
  if (tid < 256){
    qAxk_s[tid>>5][tid&31] = pf_s[tid] + pf_s[256+tid]
                           + pf_s[512+tid] + pf_s[768+tid];
  }
  if (wave >= 8){
    int h = wave - 8;
    float u0 = zz_s[h][lane], u1 = zz_s[h][lane+64];
    float s3 = b1_s[lane]*u0 + b1_s[lane+64]*u1;
    if (lane < 16) s3 += q_s[h*16+lane]*bk_s[h*16+lane];
    float qg0 = wcg_s[0][lane]*u0 + wcg_s[0][lane+64]*u1;
    float qg1 = wcg_s[1][lane]*u0 + wcg_s[1][lane+64]*u1;
    float qg2 = wcg_s[2][lane]*u0 + wcg_s[2][lane+64]*u1;
    #pragma unroll
    for (int off=32; off; off>>=1){
      s3  += __shfl_xor(s3,off);  qg0 += __shfl_xor(qg0,off);
      qg1 += __shfl_xor(qg1,off); qg2 += __shfl_xor(qg2,off);
    }
    if (lane==0){ S3_s[h]=s3; qGk_s[h][0]=qg0; qGk_s[h][1]=qg1; qGk_s[h][2]=qg2; }
  }
  __syncthreads();   // B8

  // ========= phase 9: scores in REGISTERS + per-wave max =========
  int h2 = wave>>1, sub = wave&1, n2 = lane&31, half2 = lane>>5;
  int q4 = sub*2 + half2, c0 = q4*7, c1 = (q4==3) ? NC_ : c0+7;
  float sc[7];
  {
    float qa = qAxk_s[h2][n2];
    float qg0 = qGk_s[h2][0], qg1 = qGk_s[h2][1], qg2 = qGk_s[h2][2];
    float s3 = S3_s[h2];
    bool mk = mask_s[n2] != 0;
    float M = -3.0e38f;
    #pragma unroll
    for (int t=0; t<7; t++){
      int c = c0+t;
      if (c < c1){
        int l = c*N_ + n2;
        float v = 0.25f*(is_s[l]*(qa + dc_s[0][l]*qg0 + dc_s[1][l]*qg1
                                     + dc_s[2][l]*qg2) + s3);
        sc[t] = mk ? v : -1e9f;
      } else sc[t] = -3.0e38f;
      M = fmaxf(M, sc[t]);
    }
    #pragma unroll
    for (int off=32; off; off>>=1) M = fmaxf(M, __shfl_xor(M, off));
    if (lane==0) pmax_s[h2][sub] = M;
  }
  __syncthreads();   // B10

  // ========= phase 10: exp + partial sums; prefetch Wv =========
  float4 wv4[4];
  #pragma unroll
  for (int k=0;k<4;k++)
    wv4[k] = *(const float4*)(Wv + (size_t)(es*4+k)*D_ + d4*4);
  {
    float M = fmaxf(pmax_s[h2][0], pmax_s[h2][1]);
    float S=0.f, Tn=0.f, rr0=0.f, rr1=0.f, rr2=0.f;
    #pragma unroll
    for (int t=0; t<7; t++){
      int c = c0+t;
      if (c < c1){
        int l = c*N_ + n2;
        float w_ = __expf(sc[t] - M);
        float tt = w_ * is_s[l];
        S += w_; Tn += tt;
        rr0 += tt*dc_s[0][l]; rr1 += tt*dc_s[1][l]; rr2 += tt*dc_s[2][l];
      }
    }
    float Tn2 = Tn + __shfl_xor(Tn, 32);
    if (lane < 32) Tnp_s[h2][sub][lane] = Tn2;
    #pragma unroll
    for (int off=32; off; off>>=1){
      S   += __shfl_xor(S,off);   rr0 += __shfl_xor(rr0,off);
      rr1 += __shfl_xor(rr1,off); rr2 += __shfl_xor(rr2,off);
    }
    if (lane==0){ Sp_s[h2][sub]=S;
      RDp_s[h2][sub][0]=rr0; RDp_s[h2][sub][1]=rr1; RDp_s[h2][sub][2]=rr2; }
  }
  __syncthreads();   // B11

  // ========= phase 11: ZZ_h[e]; prefetch Wo =========
  float4 wo4[4];
  #pragma unroll
  for (int k=0;k<4;k++)
    wo4[k] = *(const float4*)(Wo + (size_t)(es*4+k)*D_ + d4*4);
  {
    int h = tid>>7, e = tid&127;
    float rS = 1.f / fmaxf(Sp_s[h][0]+Sp_s[h][1], 1e-30f);
    float z = 0.f;
    #pragma unroll 8
    for (int n=0; n<N_; n++){
      float Tn = Tnp_s[h][0][n] + Tnp_s[h][1][n];
      z += Tn * xg_s[n][e];
    }
    float R0 = RDp_s[h][0][0]+RDp_s[h][1][0];
    float R1 = RDp_s[h][0][1]+RDp_s[h][1][1];
    float R2 = RDp_s[h][0][2]+RDp_s[h][1][2];
    z += R0*wcg_s[0][e] + R1*wcg_s[1][e] + R2*wcg_s[2][e];
    zz_s[h][e] = z*rS + b1_s[e];
  }
  __syncthreads();   // B12

  // ========= phase 12: Wv partials (prefetched) =========
  {
    int h = d4 >> 2;                   // uniform over the 4 output d's
    float4 acc = {0.f,0.f,0.f,0.f};
    #pragma unroll
    for (int k=0;k<4;k++){
      float zv = zz_s[h][es*4+k];
      acc.x += zv*wv4[k].x; acc.y += zv*wv4[k].y;
      acc.z += zv*wv4[k].z; acc.w += zv*wv4[k].w;
    }
    pf4[es*32 + d4] = acc;
  }
  __syncthreads();   // B13

  // ========= phase 13: att combine =========
  if (tid < D_){
    float a = bv_s[tid];
    #pragma unroll
    for (int s=0;s<32;s++) a += pf_s[s*D_+tid];
    att_s[tid] = a;
  }
  __syncthreads();   // B14

  // ========= phase 14: Wo partials (prefetched) =========
  {
    float4 acc = {0.f,0.f,0.f,0.f};
    #pragma unroll
    for (int k=0;k<4;k++){
      float av = att_s[es*4+k];
      acc.x += av*wo4[k].x; acc.y += av*wo4[k].y;
      acc.z += av*wo4[k].z; acc.w += av*wo4[k].w;
    }
    pf4[es*32 + d4] = acc;
  }
  __syncthreads();   // B15

  // ========= phase 15: prefetch W1 (all waves); y + LN2 (wave 0) =========
  float4 w14[16];
  {
    int e8 = tid>>7, c4 = tid&127;     // 8 e-slots x 128 col4-groups
    #pragma unroll
    for (int k=0;k<16;k++)
      w14[k] = *(const float4*)(W1 + (size_t)(e8*16+k)*DFF_ + c4*4);
  }
  if (wave == 0){
    float y0 = xi0 + bp_s[lane]    + bo_s[lane];
    float y1 = xi1 + bp_s[lane+64] + bo_s[lane+64];
    #pragma unroll
    for (int s=0;s<32;s++){ y0 += pf_s[s*D_+lane]; y1 += pf_s[s*D_+lane+64]; }
    y_s[lane] = y0; y_s[lane+64] = y1;
    float mean = wred(y0+y1)*(1.f/D_);
    float v0 = y0-mean, v1 = y1-mean;
    float var = wred(v0*v0+v1*v1)*(1.f/D_);
    float isd = rsqrtf(var + 1e-5f);
    hn2_s[lane]    = v0*isd*g2_s[lane]    + b2_s[lane];
    hn2_s[lane+64] = v1*isd*g2_s[lane+64] + b2_s[lane+64];
  }
  __syncthreads();   // B16

  // ========= phase 16: FFN1 partials (prefetched W1) =========
  {
    int e8 = tid>>7, c4 = tid&127;
    float4 acc = {0.f,0.f,0.f,0.f};
    #pragma unroll
    for (int k=0;k<16;k++){
      float h = hn2_s[e8*16+k];
      acc.x += h*w14[k].x; acc.y += h*w14[k].y;
      acc.z += h*w14[k].z; acc.w += h*w14[k].w;
    }
    pf4[e8*128 + c4] = acc;            // pf as [8][512]
  }
  __syncthreads();   // B17

  // ========= phase 17: relu combine; prefetch W2 =========
  float4 w24[16];
  {
    int js = tid>>5;                   // 32 j-slots x 32 d4
    #pragma unroll
    for (int k=0;k<16;k++)
      w24[k] = *(const float4*)(W2 + (size_t)(js*16+k)*D_ + d4*4);
  }
  if (tid < DFF_){
    float a = bf1_s[tid];
    #pragma unroll
    for (int s=0;s<8;s++) a += pf_s[s*DFF_+tid];
    f_s[tid] = fmaxf(a, 0.f);
  }
  __syncthreads();   // B18

  // ========= phase 18: FFN2 partials (prefetched W2) =========
  {
    int js = tid>>5;
    float4 acc = {0.f,0.f,0.f,0.f};
    #pragma unroll
    for (int k=0;k<16;k++){
      float fv = f_s[js*16+k];
      acc.x += fv*w24[k].x; acc.y += fv*w24[k].y;
      acc.z += fv*w24[k].z; acc.w += fv*w24[k].w;
    }
    pf4[js*32 + d4] = acc;             // pf as [32][128]
  }
  __syncthreads();   // B19

  // ========= phase 19: out =========
  if (tid < D_){
    float a = y_s[tid] + bfb2_s[tid];
    #pragma unroll
    for (int s=0;s<32;s++) a += pf_s[s*D_+tid];
    out[(size_t)bi*D_ + tid] = a;
  }
}

extern "C" void kernel_launch(void* const* d_in, const int* in_sizes, int n_in,
                              void* d_out, int out_size, void* d_ws, size_t ws_size,
                              hipStream_t stream){
  const float* x      = (const float*)d_in[0];
  const int*   mask   = (const int*)  d_in[1];
  const float* coords = (const float*)d_in[2];
  const float* Wp     = (const float*)d_in[3];
  const float* bp     = (const float*)d_in[4];
  const float* Wq     = (const float*)d_in[5];
  const float* bq     = (const float*)d_in[6];
  const float* Wk     = (const float*)d_in[7];
  const float* bk     = (const float*)d_in[8];
  const float* Wv     = (const float*)d_in[9];
  const float* bv     = (const float*)d_in[10];
  const float* Wo     = (const float*)d_in[11];
  const float* bo     = (const float*)d_in[12];
  const float* g1     = (const float*)d_in[13];
  const float* b1     = (const float*)d_in[14];
  const float* g2     = (const float*)d_in[15];
  const float* b2     = (const float*)d_in[16];
  const float* W1     = (const float*)d_in[17];
  const float* bf1    = (const float*)d_in[18];
  const float* W2     = (const float*)d_in[19];
  const float* bfb2   = (const float*)d_in[20];

  k_fused<<<B_*N_, 1024, 0, stream>>>(x, mask, coords, Wp, bp, Wq, bq, Wk, bk,
                                      Wv, bv, Wo, bo, g1, b1, g2, b2,
                                      W1, bf1, W2, bfb2, (float*)d_out);
}